// Round 1
// baseline (343.387 us; speedup 1.0000x reference)
//
#include <hip/hip_runtime.h>
#include <hip/hip_fp16.h>
#include <cstddef>
#include <cstdint>

#define SNL_N 50000
#define SNL_K 32
#define SNL_D 128
#define SNL_EPS 1e-12f
#define ROWS_PB 25
#define NBLK 2000          // 25 rows/block * 2000 = 50000 exactly; 8 blocks/CU co-resident
#define NPASS 8
#define BUCKET 6250        // fp16 bucket = 1.6 MB << 4 MiB L2/XCD
#define NITEM (ROWS_PB * SNL_K)   // 800 items/block; code fits 10 bits
#define YIPAD 136          // yi LDS row pitch in halves
#define WS_CTR_OFF 8192
#define WS_FP16_OFF 16384

typedef __attribute__((address_space(1))) const void gas_void;
typedef __attribute__((address_space(3))) void las_void;

__device__ __forceinline__ float dot2acc(__half2 a, __half2 b, float c) {
#if __has_builtin(__builtin_amdgcn_fdot2)
    return __builtin_amdgcn_fdot2(a, b, c, false);
#else
    float2 fa = __half22float2(a), fb = __half22float2(b);
    c = fmaf(fa.x, fb.x, c);
    return fmaf(fa.y, fb.y, c);
#endif
}

__device__ __forceinline__ float snl_dot16(const float4& yiv0, const float4& yiv1,
                                           const float4& yjv0, const float4& yjv1) {
    float acc = 0.0f;
    const __half2* hi0 = reinterpret_cast<const __half2*>(&yiv0);
    const __half2* hj0 = reinterpret_cast<const __half2*>(&yjv0);
    const __half2* hi1 = reinterpret_cast<const __half2*>(&yiv1);
    const __half2* hj1 = reinterpret_cast<const __half2*>(&yjv1);
#pragma unroll
    for (int u = 0; u < 4; ++u) {
        const __half2 d = __hsub2(hi0[u], hj0[u]);
        acc = dot2acc(d, d, acc);
    }
#pragma unroll
    for (int u = 0; u < 4; ++u) {
        const __half2 d = __hsub2(hi1[u], hj1[u]);
        acc = dot2acc(d, d, acc);
    }
    return acc;
}

// fire-and-forget L2 warm: per-lane global addr -> dummy LDS scratch (never read).
// Issued at END of pass p for bucket of pass p+1; the vmcnt wait lands on the
// NEXT pass's first gather, a full item-loop later.
__device__ __forceinline__ void dma_pref_slice(const float4* gh4, int bkt, int xsub,
                                               int tid, float4* pscratch) {
    const size_t pbase = ((size_t)bkt * BUCKET + (size_t)xsub * ROWS_PB) * 16;
    int iA = tid;                       // 0..255  (< 400 always)
    int iB = 256 + tid;                 // 256..511, clamp dup to 0 past 400
    if (iB >= ROWS_PB * 16) iB = 0;
    __builtin_amdgcn_global_load_lds((gas_void*)(const void*)(gh4 + pbase + iA),
                                     (las_void*)(void*)pscratch, 16, 0, 0);
    __builtin_amdgcn_global_load_lds((gas_void*)(const void*)(gh4 + pbase + iB),
                                     (las_void*)(void*)pscratch, 16, 0, 0);
}

// ---------------- fused kernel: quant + device barrier + passes + reduce -----
// r8 item-loop structure preserved verbatim (64-step unroll x2 + 32 tail).
// New: (a) each block quantizes its OWN 25 rows (fp32->fp16 to gh + yib LDS),
// device-wide arrive/spin barrier replaces the snl_quant launch; (b) bucket
// order staggered per XCD (b&7) so 8 XCDs stream 8 different buckets -> LLC
// dedupes HBM refetch; (c) global_load_lds dummy prefetch (no vmcnt stall at
// issue site); (d) last-block loss reduce replaces snl_loss_reduce launch.
__global__ __launch_bounds__(256, 8) void snl_fused(
    const float* __restrict__ emb,
    const float* __restrict__ psim,
    const int* __restrict__ aidx,
    float* __restrict__ out,
    float* __restrict__ part,
    __half* __restrict__ gh,
    int* __restrict__ ctr)   // ctr[0]=arrive, ctr[1]=done (memset to 0)
{
    const int tid = threadIdx.x;
    const int b   = blockIdx.x;
    const int i0  = b * ROWS_PB;

    __shared__ __half         yib[ROWS_PB * YIPAD];  // 6800 B
    __shared__ float          d2b[NITEM];            // 3200 B
    __shared__ unsigned short idb[NITEM];            // 1600 B
    __shared__ unsigned int   lst[NITEM];            // 3200 B: (a<<10)|(r*32+k)
    __shared__ int cnt[NPASS], offs[NPASS + 1], wrk[NPASS];
    __shared__ float bred[4];
    __shared__ double sred[4];
    __shared__ int lastflag;
    __shared__ float4 pscratch[64];                  // 1 KB DMA dump, never read

    const float4* emb4 = reinterpret_cast<const float4*>(emb);
    uint2*        gh2  = reinterpret_cast<uint2*>(gh);
    const float4* gh4  = reinterpret_cast<const float4*>(gh);

    // ---- phase A: quantize my 25 rows -> gh (global) + yib (LDS) ----
    // 800 float4 of fp32 -> 800 uint2 (4 halves each). Same __floats2half2_rn
    // as the old snl_quant -> bit-identical numerics.
    for (int it = 0; it < 4; ++it) {
        const int idx = it * 256 + tid;
        if (idx < ROWS_PB * 32) {
            const int row = idx >> 5, q = idx & 31;
            const float4 v = emb4[(size_t)(i0 + row) * 32 + q];
            __half2 h0 = __floats2half2_rn(v.x, v.y);
            __half2 h1 = __floats2half2_rn(v.z, v.w);
            uint2 pk;
            pk.x = *reinterpret_cast<unsigned int*>(&h0);
            pk.y = *reinterpret_cast<unsigned int*>(&h1);
            gh2[(size_t)(i0 + row) * 32 + q] = pk;
            *reinterpret_cast<uint2*>(&yib[row * YIPAD + q * 4]) = pk;
        }
    }
    for (int it = 0; it < 4; ++it) {
        const int idx = it * 256 + tid;
        if (idx < NITEM)
            idb[idx] = (unsigned short)aidx[(size_t)i0 * SNL_K + idx];
    }
    if (tid < NPASS) cnt[tid] = 0;
    __syncthreads();   // drains vmcnt -> my gh stores are in L2

    // arrive EARLY (release writes back dirty L2), then overlap the sort with
    // other blocks' phase A
    if (tid == 0)
        __hip_atomic_fetch_add(&ctr[0], 1, __ATOMIC_RELEASE, __HIP_MEMORY_SCOPE_AGENT);

    // ---- counting sort of (r,k) by bucket(anchor), anchor fused in entry ----
    for (int it = 0; it < 4; ++it) {
        const int idx = it * 256 + tid;
        if (idx < NITEM) atomicAdd(&cnt[idb[idx] / BUCKET], 1);
    }
    __syncthreads();
    if (tid == 0) {
        int acc = 0;
        for (int p = 0; p < NPASS; ++p) { offs[p] = acc; wrk[p] = acc; acc += cnt[p]; }
        offs[NPASS] = acc;
    }
    __syncthreads();
    for (int it = 0; it < 4; ++it) {
        const int idx = it * 256 + tid;
        if (idx < NITEM) {
            const unsigned a = idb[idx];
            lst[atomicAdd(&wrk[a / BUCKET], 1)] = (a << 10) | (unsigned)idx;
        }
    }
    __syncthreads();

    // ---- device-wide barrier: wait until all 2000 blocks published fp16 ----
    // Guaranteed co-resident: launch_bounds(256,8) => VGPR<=64, LDS ~16KB
    // => 8 blocks/CU * 256 CU = 2048 slots >= 2000 blocks.
    if (tid == 0) {
        while (__hip_atomic_load(&ctr[0], __ATOMIC_ACQUIRE, __HIP_MEMORY_SCOPE_AGENT) < NBLK)
            __builtin_amdgcn_s_sleep(1);
    }
    __syncthreads();

    // ---- self-paced bucket passes, XCD-staggered ----
    const int oct  = tid >> 3;   // item slot in a 32-item step (0..31)
    const int dc   = tid & 7;    // 16B chunk; 8 lanes = one 256B fp16 row
    const int xcd  = b & 7;      // blockIdx%8 ~ XCD
    const int xsub = b >> 3;     // 0..249: slice within my XCD group

    dma_pref_slice(gh4, xcd, xsub, tid, pscratch);   // prologue: my first bucket

#pragma unroll 1
    for (int p = 0; p < NPASS; ++p) {
        const int pe = (p + xcd) & 7;   // stagger: XCDs walk different buckets
        const int s0 = offs[pe], s1 = offs[pe + 1];
        const int nfull = (s1 - s0) & ~63;
        int base = s0;
#pragma unroll 1
        for (; base < s0 + nfull; base += 64) {
            const unsigned e0 = lst[base + oct];
            const unsigned e1 = lst[base + 32 + oct];
            const int code0 = (int)(e0 & 1023u), r0 = code0 >> 5, a0 = (int)(e0 >> 10);
            const int code1 = (int)(e1 & 1023u), r1 = code1 >> 5, a1 = (int)(e1 >> 10);
            const float4* jr0 = gh4 + (size_t)a0 * 16;
            const float4* jr1 = gh4 + (size_t)a1 * 16;
            const float4 gj00 = jr0[dc], gj01 = jr0[dc + 8];
            const float4 gj10 = jr1[dc], gj11 = jr1[dc + 8];
            const float4 yi00 = *reinterpret_cast<const float4*>(&yib[r0 * YIPAD + dc * 8]);
            const float4 yi01 = *reinterpret_cast<const float4*>(&yib[r0 * YIPAD + (dc + 8) * 8]);
            const float4 yi10 = *reinterpret_cast<const float4*>(&yib[r1 * YIPAD + dc * 8]);
            const float4 yi11 = *reinterpret_cast<const float4*>(&yib[r1 * YIPAD + (dc + 8) * 8]);
            float acc0 = snl_dot16(yi00, yi01, gj00, gj01);
            float acc1 = snl_dot16(yi10, yi11, gj10, gj11);
            acc0 += __shfl_xor(acc0, 1, 64);
            acc1 += __shfl_xor(acc1, 1, 64);
            acc0 += __shfl_xor(acc0, 2, 64);
            acc1 += __shfl_xor(acc1, 2, 64);
            acc0 += __shfl_xor(acc0, 4, 64);
            acc1 += __shfl_xor(acc1, 4, 64);
            if (dc == 0) {
                d2b[code0] = acc0;
                d2b[code1] = acc1;
            }
        }
#pragma unroll 1
        for (; base < s1; base += 32) {
            const int item = base + oct;
            if (item < s1) {
                const unsigned e = lst[item];
                const int code = (int)(e & 1023u);
                const int r    = code >> 5;
                const int a    = (int)(e >> 10);
                const float4* jr = gh4 + (size_t)a * 16;
                const float4 gj0 = jr[dc], gj1 = jr[dc + 8];
                const float4 yi0 = *reinterpret_cast<const float4*>(&yib[r * YIPAD + dc * 8]);
                const float4 yi1 = *reinterpret_cast<const float4*>(&yib[r * YIPAD + (dc + 8) * 8]);
                float acc = snl_dot16(yi0, yi1, gj0, gj1);
                acc += __shfl_xor(acc, 1, 64);
                acc += __shfl_xor(acc, 2, 64);
                acc += __shfl_xor(acc, 4, 64);
                if (dc == 0) d2b[code] = acc;
            }
        }
        // prefetch NEXT pass's bucket (fire-and-forget; consumed next pass)
        if (p + 1 < NPASS)
            dma_pref_slice(gh4, (pe + 1) & 7, xsub, tid, pscratch);
    }
    __syncthreads();

    // ---- softmax + outputs (one wave per row, round-robin) ----
    const int wid  = tid >> 6;
    const int lane = tid & 63;
    float loss_acc = 0.0f;
    for (int r = wid; r < ROWS_PB; r += 4) {
        const int i = i0 + r;
        const float d2 = d2b[r * SNL_K + (lane & 31)];
        const float s = -d2;
        float m = s;
#pragma unroll
        for (int off = 1; off < 32; off <<= 1)
            m = fmaxf(m, __shfl_xor(m, off, 64));
        const float e = __expf(s - m);
        float ss = e;
#pragma unroll
        for (int off = 1; off < 32; off <<= 1)
            ss += __shfl_xor(ss, off, 64);
        const float logq = (s - m) - __logf(ss);
        const float q = e / ss;
        if (lane < SNL_K) {
            out[1 + (size_t)i * SNL_K + lane] = q;
            const float pv = psim[(size_t)i * SNL_K + lane];
            loss_acc += pv * (__logf(pv + SNL_EPS) - logq);
        }
    }

#pragma unroll
    for (int off = 1; off < 64; off <<= 1)
        loss_acc += __shfl_xor(loss_acc, off, 64);
    if (lane == 0) bred[wid] = loss_acc;
    __syncthreads();

    // ---- last-block loss reduction (same order as old snl_loss_reduce) ----
    if (tid == 0) {
        part[b] = bred[0] + bred[1] + bred[2] + bred[3];
        const int old = __hip_atomic_fetch_add(&ctr[1], 1, __ATOMIC_ACQ_REL,
                                               __HIP_MEMORY_SCOPE_AGENT);
        lastflag = (old == NBLK - 1) ? 1 : 0;
    }
    __syncthreads();
    if (lastflag) {
        double acc = 0.0;
        for (int i = tid; i < NBLK; i += 256) acc += (double)part[i];
#pragma unroll
        for (int off = 1; off < 64; off <<= 1)
            acc += __shfl_xor(acc, off, 64);
        if ((tid & 63) == 0) sred[tid >> 6] = acc;
        __syncthreads();
        if (tid == 0)
            out[0] = (float)((sred[0] + sred[1] + sred[2] + sred[3]) / (double)SNL_N);
    }
}

// ---------------- fallback: fp32 kernel (if ws too small) -------------------
#define F32_ROWS 50
#define F32_NBLK 1000
#define F32_NPASS 8
#define F32_BUCKET 6250
__global__ __launch_bounds__(256, 4) void snl_main_f32(
    const float* __restrict__ emb,
    const float* __restrict__ psim,
    const int* __restrict__ aidx,
    float* __restrict__ out,
    float* __restrict__ part)
{
    const int tid = threadIdx.x;
    const int b   = blockIdx.x;
    const int i0  = b * F32_ROWS;

    __shared__ float          yib[F32_ROWS * SNL_D];
    __shared__ float          d2b[F32_ROWS * SNL_K];
    __shared__ unsigned short idb[F32_ROWS * SNL_K];
    __shared__ unsigned short lst[F32_ROWS * SNL_K];
    __shared__ int cnt[F32_NPASS], offs[F32_NPASS + 1], wrk[F32_NPASS];
    __shared__ float bred[4];

    const float4* emb4 = reinterpret_cast<const float4*>(emb);

    for (int it = 0; it < 7; ++it) {
        const int idx = it * 256 + tid;
        if (idx < F32_ROWS * SNL_D / 4)
            reinterpret_cast<float4*>(yib)[idx] = emb4[(size_t)i0 * (SNL_D / 4) + idx];
        if (idx < F32_ROWS * SNL_K)
            idb[idx] = (unsigned short)aidx[(size_t)i0 * SNL_K + idx];
    }
    if (tid < F32_NPASS) cnt[tid] = 0;
    __syncthreads();
    for (int it = 0; it < 7; ++it) {
        const int idx = it * 256 + tid;
        if (idx < F32_ROWS * SNL_K) atomicAdd(&cnt[idb[idx] / F32_BUCKET], 1);
    }
    __syncthreads();
    if (tid == 0) {
        int acc = 0;
        for (int p = 0; p < F32_NPASS; ++p) { offs[p] = acc; wrk[p] = acc; acc += cnt[p]; }
        offs[F32_NPASS] = acc;
    }
    __syncthreads();
    for (int it = 0; it < 7; ++it) {
        const int idx = it * 256 + tid;
        if (idx < F32_ROWS * SNL_K) {
            const int p = idb[idx] / F32_BUCKET;
            lst[atomicAdd(&wrk[p], 1)] = (unsigned short)idx;
        }
    }
    __syncthreads();

    const int oct  = tid >> 3;
    const int dc   = tid & 7;
    const int xsub = b >> 3;
    float pf = 0.0f;

#pragma unroll 1
    for (int p = 0; p < F32_NPASS; ++p) {
        const size_t pbase4 = ((size_t)p * F32_BUCKET + (size_t)xsub * 50) * (SNL_D / 4);
        for (int it = 0; it < 7; ++it) {
            const int idx = it * 256 + tid;
            if (idx < 50 * SNL_D / 4) pf += emb4[pbase4 + idx].x;
        }
        const int s0 = offs[p], s1 = offs[p + 1];
        for (int base = s0; base < s1; base += 32) {
            const int item = base + oct;
            if (item < s1) {
                const int code = (int)lst[item];
                const int r = code >> 5;
                const int a = (int)idb[code];
                const float4* jr = emb4 + (size_t)a * (SNL_D / 4);
                float acc = 0.0f;
#pragma unroll
                for (int it = 0; it < 4; ++it) {
                    const float4 yj = jr[dc + it * 8];
                    const float4 yi =
                        reinterpret_cast<const float4*>(yib)[r * (SNL_D / 4) + dc + it * 8];
                    const float dx = yi.x - yj.x;
                    const float dy = yi.y - yj.y;
                    const float dz = yi.z - yj.z;
                    const float dw = yi.w - yj.w;
                    acc = fmaf(dx, dx, acc);
                    acc = fmaf(dy, dy, acc);
                    acc = fmaf(dz, dz, acc);
                    acc = fmaf(dw, dw, acc);
                }
                acc += __shfl_xor(acc, 1, 64);
                acc += __shfl_xor(acc, 2, 64);
                acc += __shfl_xor(acc, 4, 64);
                if (dc == 0) d2b[code] = acc;
            }
        }
    }
    __syncthreads();

    const int wid  = tid >> 6;
    const int lane = tid & 63;
    float loss_acc = 0.0f;
    for (int r = wid; r < F32_ROWS; r += 4) {
        const int i = i0 + r;
        const float d2 = d2b[r * SNL_K + (lane & 31)];
        const float s = -d2;
        float m = s;
#pragma unroll
        for (int off = 1; off < 32; off <<= 1)
            m = fmaxf(m, __shfl_xor(m, off, 64));
        const float e = __expf(s - m);
        float ss = e;
#pragma unroll
        for (int off = 1; off < 32; off <<= 1)
            ss += __shfl_xor(ss, off, 64);
        const float logq = (s - m) - __logf(ss);
        const float q = e / ss;
        if (lane < SNL_K) {
            out[1 + (size_t)i * SNL_K + lane] = q;
            const float pv = psim[(size_t)i * SNL_K + lane];
            loss_acc += pv * (__logf(pv + SNL_EPS) - logq);
        }
    }
    __asm__ volatile("" :: "v"(pf));
#pragma unroll
    for (int off = 1; off < 64; off <<= 1)
        loss_acc += __shfl_xor(loss_acc, off, 64);
    if (lane == 0) bred[wid] = loss_acc;
    __syncthreads();
    if (tid == 0) part[b] = bred[0] + bred[1] + bred[2] + bred[3];
}

__global__ __launch_bounds__(256) void snl_loss_reduce(const float* __restrict__ part,
                                                       int npart,
                                                       float* __restrict__ out) {
    double acc = 0.0;
    for (int i = threadIdx.x; i < npart; i += 256) acc += (double)part[i];
#pragma unroll
    for (int off = 1; off < 64; off <<= 1)
        acc += __shfl_xor(acc, off, 64);
    __shared__ double sred[4];
    if ((threadIdx.x & 63) == 0) sred[threadIdx.x >> 6] = acc;
    __syncthreads();
    if (threadIdx.x == 0)
        out[0] = (float)((sred[0] + sred[1] + sred[2] + sred[3]) / (double)SNL_N);
}

extern "C" void kernel_launch(void* const* d_in, const int* in_sizes, int n_in,
                              void* d_out, int out_size, void* d_ws, size_t ws_size,
                              hipStream_t stream) {
    const float* emb  = (const float*)d_in[0];
    const float* psim = (const float*)d_in[1];
    const int*   aidx = (const int*)d_in[2];
    float* out  = (float*)d_out;
    float* part = (float*)d_ws;   // first 8 KB (NBLK floats)

    const size_t need = (size_t)WS_FP16_OFF + (size_t)SNL_N * SNL_D * sizeof(__half);
    if (ws_size >= need) {
        __half* gh = (__half*)((char*)d_ws + WS_FP16_OFF);
        int* ctr = (int*)((char*)d_ws + WS_CTR_OFF);
        hipMemsetAsync(ctr, 0, 16, stream);
        snl_fused<<<NBLK, 256, 0, stream>>>(emb, psim, aidx, out, part, gh, ctr);
    } else {
        snl_main_f32<<<F32_NBLK, 256, 0, stream>>>(emb, psim, aidx, out, part);
        snl_loss_reduce<<<1, 256, 0, stream>>>(part, F32_NBLK, out);
    }
}

// Round 2
// 186.680 us; speedup vs baseline: 1.8394x; 1.8394x over previous
//
#include <hip/hip_runtime.h>
#include <hip/hip_fp16.h>
#include <cstddef>
#include <cstdint>

#define SNL_N 50000
#define SNL_K 32
#define SNL_D 128
#define SNL_EPS 1e-12f
#define ROWS_PB 25
#define NBLK 2000          // ~16KB LDS -> 8 blocks/CU (wave-capped) -> all co-resident
#define NPASS 8
#define BUCKET 6250        // fp16 bucket = 1.6 MB << 4 MiB L2/XCD
#define NITEM (ROWS_PB * SNL_K)   // 800 items/block; code fits 10 bits
#define YIPAD 136          // yi LDS row pitch in halves
#define WS_CTR_OFF 8192
#define WS_FP16_OFF 16384

typedef __attribute__((address_space(1))) const void gas_void;
typedef __attribute__((address_space(3))) void las_void;

// ---------------- fp16 quantization pre-pass (25.6 MB -> 12.8 MB) ----------
__global__ __launch_bounds__(256) void snl_quant(const float* __restrict__ emb,
                                                 __half* __restrict__ gh) {
    const int total = SNL_N * SNL_D / 4;   // float4 items
    for (int idx = blockIdx.x * 256 + threadIdx.x; idx < total; idx += gridDim.x * 256) {
        const float4 v = reinterpret_cast<const float4*>(emb)[idx];
        __half2 h0 = __floats2half2_rn(v.x, v.y);
        __half2 h1 = __floats2half2_rn(v.z, v.w);
        uint2 pk;
        pk.x = *reinterpret_cast<unsigned int*>(&h0);
        pk.y = *reinterpret_cast<unsigned int*>(&h1);
        reinterpret_cast<uint2*>(gh)[idx] = pk;
    }
}

__device__ __forceinline__ float dot2acc(__half2 a, __half2 b, float c) {
#if __has_builtin(__builtin_amdgcn_fdot2)
    return __builtin_amdgcn_fdot2(a, b, c, false);
#else
    float2 fa = __half22float2(a), fb = __half22float2(b);
    c = fmaf(fa.x, fb.x, c);
    return fmaf(fa.y, fb.y, c);
#endif
}

__device__ __forceinline__ float snl_dot16(const float4& yiv0, const float4& yiv1,
                                           const float4& yjv0, const float4& yjv1) {
    float acc = 0.0f;
    const __half2* hi0 = reinterpret_cast<const __half2*>(&yiv0);
    const __half2* hj0 = reinterpret_cast<const __half2*>(&yjv0);
    const __half2* hi1 = reinterpret_cast<const __half2*>(&yiv1);
    const __half2* hj1 = reinterpret_cast<const __half2*>(&yjv1);
#pragma unroll
    for (int u = 0; u < 4; ++u) {
        const __half2 d = __hsub2(hi0[u], hj0[u]);
        acc = dot2acc(d, d, acc);
    }
#pragma unroll
    for (int u = 0; u < 4; ++u) {
        const __half2 d = __hsub2(hi1[u], hj1[u]);
        acc = dot2acc(d, d, acc);
    }
    return acc;
}

// fire-and-forget L2 warm: per-lane global addr -> dummy LDS scratch (never
// read). No VGPR result, no dependency chain -> no wait anywhere inside the
// pass loop (no __syncthreads until after all passes).
__device__ __forceinline__ void dma_pref_slice(const float4* gh4, int bkt, int xsub,
                                               int tid, float4* pscratch) {
    const size_t pbase = ((size_t)bkt * BUCKET + (size_t)xsub * ROWS_PB) * 16;
    int iA = tid;                       // 0..255  (< 400 always)
    int iB = 256 + tid;                 // 256..399, clamp dup to 0 past 400
    if (iB >= ROWS_PB * 16) iB = 0;
    __builtin_amdgcn_global_load_lds((gas_void*)(const void*)(gh4 + pbase + iA),
                                     (las_void*)(void*)pscratch, 16, 0, 0);
    __builtin_amdgcn_global_load_lds((gas_void*)(const void*)(gh4 + pbase + iB),
                                     (las_void*)(void*)pscratch, 16, 0, 0);
}

// ---------------- main bucketed-pass kernel ---------------------------------
// r8 item-loop structure preserved verbatim (47 us best: 2000 blocks, NPASS=8
// bucket passes, hsub2+fdot2 inner loop, 64-item unrolled steps + 32 tail).
// Round-2 changes (NO device barrier -- round-1's spin barrier regressed 6x):
// (a) XCD-staggered bucket order: XCD x walks buckets (x, x+1, ...) mod 8 so
//     8 different buckets stream concurrently -> LLC dedupes HBM refetch
//     (round-0 FETCH was 74.5 MB vs ~26 MB ideal from lockstep walk);
// (b) global_load_lds dummy prefetch replaces pf-accumulating prefetch
//     (fire-and-forget, zero VGPR, issued at END of pass p for pass p+1);
// (c) last-block loss reduce via done-counter (needs only release/acquire
//     ordering, NOT co-residency) -> removes the snl_loss_reduce dispatch.
__global__ __launch_bounds__(256, 8) void snl_main_h(
    const __half* __restrict__ gh,
    const float* __restrict__ psim,
    const int* __restrict__ aidx,
    float* __restrict__ out,
    float* __restrict__ part,
    int* __restrict__ ctr)   // ctr[0]=done counter (memset to 0)
{
    const int tid = threadIdx.x;
    const int b   = blockIdx.x;
    const int i0  = b * ROWS_PB;

    __shared__ __half         yib[ROWS_PB * YIPAD];  // 6800 B
    __shared__ float          d2b[NITEM];            // 3200 B
    __shared__ unsigned short idb[NITEM];            // 1600 B
    __shared__ unsigned int   lst[NITEM];            // 3200 B: (a<<10)|(r*32+k)
    __shared__ int cnt[NPASS], offs[NPASS + 1], wrk[NPASS];
    __shared__ float bred[4];
    __shared__ double sred[4];
    __shared__ int lastflag;
    __shared__ float4 pscratch[64];                  // 1 KB DMA dump, never read

    const float4* gh4 = reinterpret_cast<const float4*>(gh);  // 16B = 8 halves

    // ---- stage yi (400 x 16B chunks) + ids (800) ----
    for (int it = 0; it < 2; ++it) {
        const int idx = it * 256 + tid;
        if (idx < ROWS_PB * 16) {
            const int row = idx >> 4, c = idx & 15;
            *reinterpret_cast<float4*>(&yib[row * YIPAD + c * 8]) =
                gh4[(size_t)(i0 + row) * 16 + c];
        }
    }
    for (int it = 0; it < 4; ++it) {
        const int idx = it * 256 + tid;
        if (idx < NITEM)
            idb[idx] = (unsigned short)aidx[(size_t)i0 * SNL_K + idx];
    }
    if (tid < NPASS) cnt[tid] = 0;
    __syncthreads();

    // ---- counting sort of (r,k) by bucket(anchor), anchor fused in entry ----
    for (int it = 0; it < 4; ++it) {
        const int idx = it * 256 + tid;
        if (idx < NITEM) atomicAdd(&cnt[idb[idx] / BUCKET], 1);
    }
    __syncthreads();
    if (tid == 0) {
        int acc = 0;
        for (int p = 0; p < NPASS; ++p) { offs[p] = acc; wrk[p] = acc; acc += cnt[p]; }
        offs[NPASS] = acc;
    }
    __syncthreads();
    for (int it = 0; it < 4; ++it) {
        const int idx = it * 256 + tid;
        if (idx < NITEM) {
            const unsigned a = idb[idx];
            lst[atomicAdd(&wrk[a / BUCKET], 1)] = (a << 10) | (unsigned)idx;
        }
    }
    __syncthreads();

    // ---- self-paced bucket passes, XCD-staggered ----
    const int oct  = tid >> 3;   // item slot in a 32-item step (0..31)
    const int dc   = tid & 7;    // 16B chunk; 8 lanes = one 256B fp16 row
    const int xcd  = b & 7;      // blockIdx%8 ~ XCD
    const int xsub = b >> 3;     // 0..249: slice within my XCD group

    // prologue: warm my first bucket (issued after last barrier; nothing
    // drains vmcnt until the post-pass __syncthreads)
    dma_pref_slice(gh4, xcd, xsub, tid, pscratch);

#pragma unroll 1
    for (int p = 0; p < NPASS; ++p) {
        const int pe = (p + xcd) & 7;   // stagger: XCDs walk different buckets
        const int s0 = offs[pe], s1 = offs[pe + 1];
        const int nfull = (s1 - s0) & ~63;
        int base = s0;
#pragma unroll 1
        for (; base < s0 + nfull; base += 64) {
            const unsigned e0 = lst[base + oct];
            const unsigned e1 = lst[base + 32 + oct];
            const int code0 = (int)(e0 & 1023u), r0 = code0 >> 5, a0 = (int)(e0 >> 10);
            const int code1 = (int)(e1 & 1023u), r1 = code1 >> 5, a1 = (int)(e1 >> 10);
            const float4* jr0 = gh4 + (size_t)a0 * 16;
            const float4* jr1 = gh4 + (size_t)a1 * 16;
            const float4 gj00 = jr0[dc], gj01 = jr0[dc + 8];
            const float4 gj10 = jr1[dc], gj11 = jr1[dc + 8];
            const float4 yi00 = *reinterpret_cast<const float4*>(&yib[r0 * YIPAD + dc * 8]);
            const float4 yi01 = *reinterpret_cast<const float4*>(&yib[r0 * YIPAD + (dc + 8) * 8]);
            const float4 yi10 = *reinterpret_cast<const float4*>(&yib[r1 * YIPAD + dc * 8]);
            const float4 yi11 = *reinterpret_cast<const float4*>(&yib[r1 * YIPAD + (dc + 8) * 8]);
            float acc0 = snl_dot16(yi00, yi01, gj00, gj01);
            float acc1 = snl_dot16(yi10, yi11, gj10, gj11);
            acc0 += __shfl_xor(acc0, 1, 64);
            acc1 += __shfl_xor(acc1, 1, 64);
            acc0 += __shfl_xor(acc0, 2, 64);
            acc1 += __shfl_xor(acc1, 2, 64);
            acc0 += __shfl_xor(acc0, 4, 64);
            acc1 += __shfl_xor(acc1, 4, 64);
            if (dc == 0) {
                d2b[code0] = acc0;
                d2b[code1] = acc1;
            }
        }
#pragma unroll 1
        for (; base < s1; base += 32) {
            const int item = base + oct;
            if (item < s1) {
                const unsigned e = lst[item];
                const int code = (int)(e & 1023u);
                const int r    = code >> 5;
                const int a    = (int)(e >> 10);
                const float4* jr = gh4 + (size_t)a * 16;
                const float4 gj0 = jr[dc], gj1 = jr[dc + 8];
                const float4 yi0 = *reinterpret_cast<const float4*>(&yib[r * YIPAD + dc * 8]);
                const float4 yi1 = *reinterpret_cast<const float4*>(&yib[r * YIPAD + (dc + 8) * 8]);
                float acc = snl_dot16(yi0, yi1, gj0, gj1);
                acc += __shfl_xor(acc, 1, 64);
                acc += __shfl_xor(acc, 2, 64);
                acc += __shfl_xor(acc, 4, 64);
                if (dc == 0) d2b[code] = acc;
            }
        }
        // prefetch NEXT pass's bucket (fire-and-forget; consumed next pass)
        if (p + 1 < NPASS)
            dma_pref_slice(gh4, (pe + 1) & 7, xsub, tid, pscratch);
    }
    __syncthreads();

    // ---- softmax + outputs (one wave per row, round-robin) ----
    const int wid  = tid >> 6;
    const int lane = tid & 63;
    float loss_acc = 0.0f;
    for (int r = wid; r < ROWS_PB; r += 4) {
        const int i = i0 + r;
        const float d2 = d2b[r * SNL_K + (lane & 31)];
        const float s = -d2;
        float m = s;
#pragma unroll
        for (int off = 1; off < 32; off <<= 1)
            m = fmaxf(m, __shfl_xor(m, off, 64));
        const float e = __expf(s - m);
        float ss = e;
#pragma unroll
        for (int off = 1; off < 32; off <<= 1)
            ss += __shfl_xor(ss, off, 64);
        const float logq = (s - m) - __logf(ss);
        const float q = e / ss;
        if (lane < SNL_K) {
            out[1 + (size_t)i * SNL_K + lane] = q;
            const float pv = psim[(size_t)i * SNL_K + lane];
            loss_acc += pv * (__logf(pv + SNL_EPS) - logq);
        }
    }

#pragma unroll
    for (int off = 1; off < 64; off <<= 1)
        loss_acc += __shfl_xor(loss_acc, off, 64);
    if (lane == 0) bred[wid] = loss_acc;
    __syncthreads();

    // ---- last-block loss reduction (done-counter; release/acquire pairs
    // make every part[] store visible to the last arriving block; identical
    // summation order to the old snl_loss_reduce dispatch) ----
    if (tid == 0) {
        part[b] = bred[0] + bred[1] + bred[2] + bred[3];
        const int old = __hip_atomic_fetch_add(&ctr[0], 1, __ATOMIC_ACQ_REL,
                                               __HIP_MEMORY_SCOPE_AGENT);
        lastflag = (old == NBLK - 1) ? 1 : 0;
    }
    __syncthreads();
    if (lastflag) {
        double acc = 0.0;
        for (int i = tid; i < NBLK; i += 256) acc += (double)part[i];
#pragma unroll
        for (int off = 1; off < 64; off <<= 1)
            acc += __shfl_xor(acc, off, 64);
        if ((tid & 63) == 0) sred[tid >> 6] = acc;
        __syncthreads();
        if (tid == 0)
            out[0] = (float)((sred[0] + sred[1] + sred[2] + sred[3]) / (double)SNL_N);
    }
}

// ---------------- fallback: fp32 kernel (if ws too small) -------------------
#define F32_ROWS 50
#define F32_NBLK 1000
#define F32_NPASS 8
#define F32_BUCKET 6250
__global__ __launch_bounds__(256, 4) void snl_main_f32(
    const float* __restrict__ emb,
    const float* __restrict__ psim,
    const int* __restrict__ aidx,
    float* __restrict__ out,
    float* __restrict__ part)
{
    const int tid = threadIdx.x;
    const int b   = blockIdx.x;
    const int i0  = b * F32_ROWS;

    __shared__ float          yib[F32_ROWS * SNL_D];
    __shared__ float          d2b[F32_ROWS * SNL_K];
    __shared__ unsigned short idb[F32_ROWS * SNL_K];
    __shared__ unsigned short lst[F32_ROWS * SNL_K];
    __shared__ int cnt[F32_NPASS], offs[F32_NPASS + 1], wrk[F32_NPASS];
    __shared__ float bred[4];

    const float4* emb4 = reinterpret_cast<const float4*>(emb);

    for (int it = 0; it < 7; ++it) {
        const int idx = it * 256 + tid;
        if (idx < F32_ROWS * SNL_D / 4)
            reinterpret_cast<float4*>(yib)[idx] = emb4[(size_t)i0 * (SNL_D / 4) + idx];
        if (idx < F32_ROWS * SNL_K)
            idb[idx] = (unsigned short)aidx[(size_t)i0 * SNL_K + idx];
    }
    if (tid < F32_NPASS) cnt[tid] = 0;
    __syncthreads();
    for (int it = 0; it < 7; ++it) {
        const int idx = it * 256 + tid;
        if (idx < F32_ROWS * SNL_K) atomicAdd(&cnt[idb[idx] / F32_BUCKET], 1);
    }
    __syncthreads();
    if (tid == 0) {
        int acc = 0;
        for (int p = 0; p < F32_NPASS; ++p) { offs[p] = acc; wrk[p] = acc; acc += cnt[p]; }
        offs[F32_NPASS] = acc;
    }
    __syncthreads();
    for (int it = 0; it < 7; ++it) {
        const int idx = it * 256 + tid;
        if (idx < F32_ROWS * SNL_K) {
            const int p = idb[idx] / F32_BUCKET;
            lst[atomicAdd(&wrk[p], 1)] = (unsigned short)idx;
        }
    }
    __syncthreads();

    const int oct  = tid >> 3;
    const int dc   = tid & 7;
    const int xsub = b >> 3;
    float pf = 0.0f;

#pragma unroll 1
    for (int p = 0; p < F32_NPASS; ++p) {
        const size_t pbase4 = ((size_t)p * F32_BUCKET + (size_t)xsub * 50) * (SNL_D / 4);
        for (int it = 0; it < 7; ++it) {
            const int idx = it * 256 + tid;
            if (idx < 50 * SNL_D / 4) pf += emb4[pbase4 + idx].x;
        }
        const int s0 = offs[p], s1 = offs[p + 1];
        for (int base = s0; base < s1; base += 32) {
            const int item = base + oct;
            if (item < s1) {
                const int code = (int)lst[item];
                const int r = code >> 5;
                const int a = (int)idb[code];
                const float4* jr = emb4 + (size_t)a * (SNL_D / 4);
                float acc = 0.0f;
#pragma unroll
                for (int it = 0; it < 4; ++it) {
                    const float4 yj = jr[dc + it * 8];
                    const float4 yi =
                        reinterpret_cast<const float4*>(yib)[r * (SNL_D / 4) + dc + it * 8];
                    const float dx = yi.x - yj.x;
                    const float dy = yi.y - yj.y;
                    const float dz = yi.z - yj.z;
                    const float dw = yi.w - yj.w;
                    acc = fmaf(dx, dx, acc);
                    acc = fmaf(dy, dy, acc);
                    acc = fmaf(dz, dz, acc);
                    acc = fmaf(dw, dw, acc);
                }
                acc += __shfl_xor(acc, 1, 64);
                acc += __shfl_xor(acc, 2, 64);
                acc += __shfl_xor(acc, 4, 64);
                if (dc == 0) d2b[code] = acc;
            }
        }
    }
    __syncthreads();

    const int wid  = tid >> 6;
    const int lane = tid & 63;
    float loss_acc = 0.0f;
    for (int r = wid; r < F32_ROWS; r += 4) {
        const int i = i0 + r;
        const float d2 = d2b[r * SNL_K + (lane & 31)];
        const float s = -d2;
        float m = s;
#pragma unroll
        for (int off = 1; off < 32; off <<= 1)
            m = fmaxf(m, __shfl_xor(m, off, 64));
        const float e = __expf(s - m);
        float ss = e;
#pragma unroll
        for (int off = 1; off < 32; off <<= 1)
            ss += __shfl_xor(ss, off, 64);
        const float logq = (s - m) - __logf(ss);
        const float q = e / ss;
        if (lane < SNL_K) {
            out[1 + (size_t)i * SNL_K + lane] = q;
            const float pv = psim[(size_t)i * SNL_K + lane];
            loss_acc += pv * (__logf(pv + SNL_EPS) - logq);
        }
    }
    __asm__ volatile("" :: "v"(pf));
#pragma unroll
    for (int off = 1; off < 64; off <<= 1)
        loss_acc += __shfl_xor(loss_acc, off, 64);
    if (lane == 0) bred[wid] = loss_acc;
    __syncthreads();
    if (tid == 0) part[b] = bred[0] + bred[1] + bred[2] + bred[3];
}

__global__ __launch_bounds__(256) void snl_loss_reduce(const float* __restrict__ part,
                                                       int npart,
                                                       float* __restrict__ out) {
    double acc = 0.0;
    for (int i = threadIdx.x; i < npart; i += 256) acc += (double)part[i];
#pragma unroll
    for (int off = 1; off < 64; off <<= 1)
        acc += __shfl_xor(acc, off, 64);
    __shared__ double sred[4];
    if ((threadIdx.x & 63) == 0) sred[threadIdx.x >> 6] = acc;
    __syncthreads();
    if (threadIdx.x == 0)
        out[0] = (float)((sred[0] + sred[1] + sred[2] + sred[3]) / (double)SNL_N);
}

extern "C" void kernel_launch(void* const* d_in, const int* in_sizes, int n_in,
                              void* d_out, int out_size, void* d_ws, size_t ws_size,
                              hipStream_t stream) {
    const float* emb  = (const float*)d_in[0];
    const float* psim = (const float*)d_in[1];
    const int*   aidx = (const int*)d_in[2];
    float* out  = (float*)d_out;
    float* part = (float*)d_ws;   // first 8 KB (NBLK floats)

    const size_t need = (size_t)WS_FP16_OFF + (size_t)SNL_N * SNL_D * sizeof(__half);
    if (ws_size >= need) {
        __half* gh = (__half*)((char*)d_ws + WS_FP16_OFF);
        int* ctr = (int*)((char*)d_ws + WS_CTR_OFF);
        hipMemsetAsync(ctr, 0, 16, stream);
        snl_quant<<<2048, 256, 0, stream>>>(emb, gh);
        snl_main_h<<<NBLK, 256, 0, stream>>>(gh, psim, aidx, out, part, ctr);
    } else {
        snl_main_f32<<<F32_NBLK, 256, 0, stream>>>(emb, psim, aidx, out, part);
        snl_loss_reduce<<<1, 256, 0, stream>>>(part, F32_NBLK, out);
    }
}

// Round 3
// 169.591 us; speedup vs baseline: 2.0248x; 1.1008x over previous
//
#include <hip/hip_runtime.h>
#include <hip/hip_fp16.h>
#include <cstddef>
#include <cstdint>

#define SNL_N 50000
#define SNL_K 32
#define SNL_D 128
#define SNL_EPS 1e-12f
#define ROWS_PB 25
#define NBLK 2000          // ~15KB LDS -> 8 blocks/CU (wave-capped) -> all co-resident
#define NPASS 8
#define BUCKET 6250        // fp16 bucket = 1.6 MB << 4 MiB L2/XCD
#define NITEM (ROWS_PB * SNL_K)   // 800 items/block; code fits 10 bits
#define YIPAD 136          // yi LDS row pitch in halves
#define WS_CTR_OFF 8192
#define WS_FP16_OFF 16384

// ---------------- fp16 quantization pre-pass (25.6 MB -> 12.8 MB) ----------
// Also zeroes the done-counter used by the fused last-block loss reduction
// (stream order quant -> main makes the zero visible; removes the memset
// dispatch).
__global__ __launch_bounds__(256) void snl_quant(const float* __restrict__ emb,
                                                 __half* __restrict__ gh,
                                                 int* __restrict__ ctr) {
    if (blockIdx.x == 0 && threadIdx.x == 0) {
        ctr[0] = 0;
        ctr[1] = 0;
    }
    const int total = SNL_N * SNL_D / 4;   // float4 items
    for (int idx = blockIdx.x * 256 + threadIdx.x; idx < total; idx += gridDim.x * 256) {
        const float4 v = reinterpret_cast<const float4*>(emb)[idx];
        __half2 h0 = __floats2half2_rn(v.x, v.y);
        __half2 h1 = __floats2half2_rn(v.z, v.w);
        uint2 pk;
        pk.x = *reinterpret_cast<unsigned int*>(&h0);
        pk.y = *reinterpret_cast<unsigned int*>(&h1);
        reinterpret_cast<uint2*>(gh)[idx] = pk;
    }
}

__device__ __forceinline__ float dot2acc(__half2 a, __half2 b, float c) {
#if __has_builtin(__builtin_amdgcn_fdot2)
    return __builtin_amdgcn_fdot2(a, b, c, false);
#else
    float2 fa = __half22float2(a), fb = __half22float2(b);
    c = fmaf(fa.x, fb.x, c);
    return fmaf(fa.y, fb.y, c);
#endif
}

__device__ __forceinline__ float snl_dot16(const float4& yiv0, const float4& yiv1,
                                           const float4& yjv0, const float4& yjv1) {
    float acc = 0.0f;
    const __half2* hi0 = reinterpret_cast<const __half2*>(&yiv0);
    const __half2* hj0 = reinterpret_cast<const __half2*>(&yjv0);
    const __half2* hi1 = reinterpret_cast<const __half2*>(&yiv1);
    const __half2* hj1 = reinterpret_cast<const __half2*>(&yjv1);
#pragma unroll
    for (int u = 0; u < 4; ++u) {
        const __half2 d = __hsub2(hi0[u], hj0[u]);
        acc = dot2acc(d, d, acc);
    }
#pragma unroll
    for (int u = 0; u < 4; ++u) {
        const __half2 d = __hsub2(hi1[u], hj1[u]);
        acc = dot2acc(d, d, acc);
    }
    return acc;
}

// ---------------- main bucketed-pass kernel ---------------------------------
// EXACT round-0 structure (45.6 us measured: 2000 co-resident blocks, NPASS=8
// SELF-PACED LOCKSTEP bucket passes -- the pf-accumulating prefetch is the
// pacing mechanism: pass p+1's pf-add can't retire until pass p's prefetch
// loads land, so blocks stay ~1 pass apart and each XCD's L2 holds exactly
// one 1.6 MB bucket. Round-2 falsified both the XCD-staggered bucket order
// and the fire-and-forget global_load_lds prefetch: blocks drifted, L2 held
// fragments of many buckets, FETCH 74.5->114.8 MB, dur 45.6->119 us.)
// Only change vs round-0: last-block loss reduction via done-counter
// (release/acquire; needs no co-residency) -> removes one dispatch.
__global__ __launch_bounds__(256, 8) void snl_main_h(
    const __half* __restrict__ gh,
    const float* __restrict__ psim,
    const int* __restrict__ aidx,
    float* __restrict__ out,
    float* __restrict__ part,
    int* __restrict__ ctr)   // ctr[0]=done counter (zeroed by snl_quant)
{
    const int tid = threadIdx.x;
    const int b   = blockIdx.x;
    const int i0  = b * ROWS_PB;

    __shared__ __half         yib[ROWS_PB * YIPAD];  // 6800 B
    __shared__ float          d2b[NITEM];            // 3200 B
    __shared__ unsigned short idb[NITEM];            // 1600 B
    __shared__ unsigned int   lst[NITEM];            // 3200 B: (a<<10)|(r*32+k)
    __shared__ int cnt[NPASS], offs[NPASS + 1], wrk[NPASS];
    __shared__ float bred[4];
    __shared__ double sred[4];
    __shared__ int lastflag;

    const float4* gh4 = reinterpret_cast<const float4*>(gh);  // 16B = 8 halves

    // ---- stage yi (400 x 16B chunks) + ids (800) ----
    for (int it = 0; it < 2; ++it) {
        const int idx = it * 256 + tid;
        if (idx < ROWS_PB * 16) {
            const int row = idx >> 4, c = idx & 15;
            *reinterpret_cast<float4*>(&yib[row * YIPAD + c * 8]) =
                gh4[(size_t)(i0 + row) * 16 + c];
        }
    }
    for (int it = 0; it < 4; ++it) {
        const int idx = it * 256 + tid;
        if (idx < NITEM)
            idb[idx] = (unsigned short)aidx[(size_t)i0 * SNL_K + idx];
    }
    if (tid < NPASS) cnt[tid] = 0;
    __syncthreads();

    // ---- counting sort of (r,k) by bucket(anchor), anchor fused in entry ----
    for (int it = 0; it < 4; ++it) {
        const int idx = it * 256 + tid;
        if (idx < NITEM) atomicAdd(&cnt[idb[idx] / BUCKET], 1);
    }
    __syncthreads();
    if (tid == 0) {
        int acc = 0;
        for (int p = 0; p < NPASS; ++p) { offs[p] = acc; wrk[p] = acc; acc += cnt[p]; }
        offs[NPASS] = acc;
    }
    __syncthreads();
    for (int it = 0; it < 4; ++it) {
        const int idx = it * 256 + tid;
        if (idx < NITEM) {
            const unsigned a = idb[idx];
            lst[atomicAdd(&wrk[a / BUCKET], 1)] = (a << 10) | (unsigned)idx;
        }
    }
    __syncthreads();

    // ---- self-paced bucket passes ----
    const int oct  = tid >> 3;   // item slot in a 32-item step (0..31)
    const int dc   = tid & 7;    // 16B chunk; 8 lanes = one 256B fp16 row
    const int xsub = b >> 3;     // 0..249: slice within my XCD group (b%8 ~ XCD)
    float pf = 0.0f;

#pragma unroll 1
    for (int p = 0; p < NPASS; ++p) {
        // prefetch my XCD-group's 25-row slice of fp16 bucket p (400 chunks;
        // 250 blocks/XCD-group x 25 rows = 6250 = full bucket). The pf chain
        // doubles as the cross-pass pacing dependency -- do not remove.
        const size_t pbase = ((size_t)p * BUCKET + (size_t)xsub * ROWS_PB) * 16;
        for (int it = 0; it < 2; ++it) {
            const int idx = it * 256 + tid;
            if (idx < ROWS_PB * 16) pf += gh4[pbase + idx].x;
        }

        // dense processing: full 64-item steps (no predication), then tail
        const int s0 = offs[p], s1 = offs[p + 1];
        const int nfull = (s1 - s0) & ~63;
        int base = s0;
#pragma unroll 1
        for (; base < s0 + nfull; base += 64) {
            const unsigned e0 = lst[base + oct];
            const unsigned e1 = lst[base + 32 + oct];
            const int code0 = (int)(e0 & 1023u), r0 = code0 >> 5, a0 = (int)(e0 >> 10);
            const int code1 = (int)(e1 & 1023u), r1 = code1 >> 5, a1 = (int)(e1 >> 10);
            const float4* jr0 = gh4 + (size_t)a0 * 16;
            const float4* jr1 = gh4 + (size_t)a1 * 16;
            const float4 gj00 = jr0[dc], gj01 = jr0[dc + 8];
            const float4 gj10 = jr1[dc], gj11 = jr1[dc + 8];
            const float4 yi00 = *reinterpret_cast<const float4*>(&yib[r0 * YIPAD + dc * 8]);
            const float4 yi01 = *reinterpret_cast<const float4*>(&yib[r0 * YIPAD + (dc + 8) * 8]);
            const float4 yi10 = *reinterpret_cast<const float4*>(&yib[r1 * YIPAD + dc * 8]);
            const float4 yi11 = *reinterpret_cast<const float4*>(&yib[r1 * YIPAD + (dc + 8) * 8]);
            float acc0 = snl_dot16(yi00, yi01, gj00, gj01);
            float acc1 = snl_dot16(yi10, yi11, gj10, gj11);
            acc0 += __shfl_xor(acc0, 1, 64);
            acc1 += __shfl_xor(acc1, 1, 64);
            acc0 += __shfl_xor(acc0, 2, 64);
            acc1 += __shfl_xor(acc1, 2, 64);
            acc0 += __shfl_xor(acc0, 4, 64);
            acc1 += __shfl_xor(acc1, 4, 64);
            if (dc == 0) {
                d2b[code0] = acc0;
                d2b[code1] = acc1;
            }
        }
#pragma unroll 1
        for (; base < s1; base += 32) {
            const int item = base + oct;
            if (item < s1) {
                const unsigned e = lst[item];
                const int code = (int)(e & 1023u);
                const int r    = code >> 5;
                const int a    = (int)(e >> 10);
                const float4* jr = gh4 + (size_t)a * 16;
                const float4 gj0 = jr[dc], gj1 = jr[dc + 8];
                const float4 yi0 = *reinterpret_cast<const float4*>(&yib[r * YIPAD + dc * 8]);
                const float4 yi1 = *reinterpret_cast<const float4*>(&yib[r * YIPAD + (dc + 8) * 8]);
                float acc = snl_dot16(yi0, yi1, gj0, gj1);
                acc += __shfl_xor(acc, 1, 64);
                acc += __shfl_xor(acc, 2, 64);
                acc += __shfl_xor(acc, 4, 64);
                if (dc == 0) d2b[code] = acc;
            }
        }
    }
    __syncthreads();

    // ---- softmax + outputs (one wave per row, round-robin) ----
    const int wid  = tid >> 6;
    const int lane = tid & 63;
    float loss_acc = 0.0f;
    for (int r = wid; r < ROWS_PB; r += 4) {
        const int i = i0 + r;
        const float d2 = d2b[r * SNL_K + (lane & 31)];
        const float s = -d2;
        float m = s;
#pragma unroll
        for (int off = 1; off < 32; off <<= 1)
            m = fmaxf(m, __shfl_xor(m, off, 64));
        const float e = __expf(s - m);
        float ss = e;
#pragma unroll
        for (int off = 1; off < 32; off <<= 1)
            ss += __shfl_xor(ss, off, 64);
        const float logq = (s - m) - __logf(ss);
        const float q = e / ss;
        if (lane < SNL_K) {
            out[1 + (size_t)i * SNL_K + lane] = q;
            const float pv = psim[(size_t)i * SNL_K + lane];
            loss_acc += pv * (__logf(pv + SNL_EPS) - logq);
        }
    }

    __asm__ volatile("" :: "v"(pf));   // keep prefetch loads alive

#pragma unroll
    for (int off = 1; off < 64; off <<= 1)
        loss_acc += __shfl_xor(loss_acc, off, 64);
    if (lane == 0) bred[wid] = loss_acc;
    __syncthreads();

    // ---- last-block loss reduction (done-counter; the acquire on the final
    // fetch_add pairs with all 1999 prior releases -> every part[] store is
    // visible; summation order identical to the old snl_loss_reduce) ----
    if (tid == 0) {
        part[b] = bred[0] + bred[1] + bred[2] + bred[3];
        const int old = __hip_atomic_fetch_add(&ctr[0], 1, __ATOMIC_ACQ_REL,
                                               __HIP_MEMORY_SCOPE_AGENT);
        lastflag = (old == NBLK - 1) ? 1 : 0;
    }
    __syncthreads();
    if (lastflag) {
        double acc = 0.0;
        for (int i = tid; i < NBLK; i += 256) acc += (double)part[i];
#pragma unroll
        for (int off = 1; off < 64; off <<= 1)
            acc += __shfl_xor(acc, off, 64);
        if ((tid & 63) == 0) sred[tid >> 6] = acc;
        __syncthreads();
        if (tid == 0)
            out[0] = (float)((sred[0] + sred[1] + sred[2] + sred[3]) / (double)SNL_N);
    }
}

// ---------------- fallback: fp32 kernel (if ws too small) -------------------
#define F32_ROWS 50
#define F32_NBLK 1000
#define F32_NPASS 8
#define F32_BUCKET 6250
__global__ __launch_bounds__(256, 4) void snl_main_f32(
    const float* __restrict__ emb,
    const float* __restrict__ psim,
    const int* __restrict__ aidx,
    float* __restrict__ out,
    float* __restrict__ part)
{
    const int tid = threadIdx.x;
    const int b   = blockIdx.x;
    const int i0  = b * F32_ROWS;

    __shared__ float          yib[F32_ROWS * SNL_D];
    __shared__ float          d2b[F32_ROWS * SNL_K];
    __shared__ unsigned short idb[F32_ROWS * SNL_K];
    __shared__ unsigned short lst[F32_ROWS * SNL_K];
    __shared__ int cnt[F32_NPASS], offs[F32_NPASS + 1], wrk[F32_NPASS];
    __shared__ float bred[4];

    const float4* emb4 = reinterpret_cast<const float4*>(emb);

    for (int it = 0; it < 7; ++it) {
        const int idx = it * 256 + tid;
        if (idx < F32_ROWS * SNL_D / 4)
            reinterpret_cast<float4*>(yib)[idx] = emb4[(size_t)i0 * (SNL_D / 4) + idx];
        if (idx < F32_ROWS * SNL_K)
            idb[idx] = (unsigned short)aidx[(size_t)i0 * SNL_K + idx];
    }
    if (tid < F32_NPASS) cnt[tid] = 0;
    __syncthreads();
    for (int it = 0; it < 7; ++it) {
        const int idx = it * 256 + tid;
        if (idx < F32_ROWS * SNL_K) atomicAdd(&cnt[idb[idx] / F32_BUCKET], 1);
    }
    __syncthreads();
    if (tid == 0) {
        int acc = 0;
        for (int p = 0; p < F32_NPASS; ++p) { offs[p] = acc; wrk[p] = acc; acc += cnt[p]; }
        offs[F32_NPASS] = acc;
    }
    __syncthreads();
    for (int it = 0; it < 7; ++it) {
        const int idx = it * 256 + tid;
        if (idx < F32_ROWS * SNL_K) {
            const int p = idb[idx] / F32_BUCKET;
            lst[atomicAdd(&wrk[p], 1)] = (unsigned short)idx;
        }
    }
    __syncthreads();

    const int oct  = tid >> 3;
    const int dc   = tid & 7;
    const int xsub = b >> 3;
    float pf = 0.0f;

#pragma unroll 1
    for (int p = 0; p < F32_NPASS; ++p) {
        const size_t pbase4 = ((size_t)p * F32_BUCKET + (size_t)xsub * 50) * (SNL_D / 4);
        for (int it = 0; it < 7; ++it) {
            const int idx = it * 256 + tid;
            if (idx < 50 * SNL_D / 4) pf += emb4[pbase4 + idx].x;
        }
        const int s0 = offs[p], s1 = offs[p + 1];
        for (int base = s0; base < s1; base += 32) {
            const int item = base + oct;
            if (item < s1) {
                const int code = (int)lst[item];
                const int r = code >> 5;
                const int a = (int)idb[code];
                const float4* jr = emb4 + (size_t)a * (SNL_D / 4);
                float acc = 0.0f;
#pragma unroll
                for (int it = 0; it < 4; ++it) {
                    const float4 yj = jr[dc + it * 8];
                    const float4 yi =
                        reinterpret_cast<const float4*>(yib)[r * (SNL_D / 4) + dc + it * 8];
                    const float dx = yi.x - yj.x;
                    const float dy = yi.y - yj.y;
                    const float dz = yi.z - yj.z;
                    const float dw = yi.w - yj.w;
                    acc = fmaf(dx, dx, acc);
                    acc = fmaf(dy, dy, acc);
                    acc = fmaf(dz, dz, acc);
                    acc = fmaf(dw, dw, acc);
                }
                acc += __shfl_xor(acc, 1, 64);
                acc += __shfl_xor(acc, 2, 64);
                acc += __shfl_xor(acc, 4, 64);
                if (dc == 0) d2b[code] = acc;
            }
        }
    }
    __syncthreads();

    const int wid  = tid >> 6;
    const int lane = tid & 63;
    float loss_acc = 0.0f;
    for (int r = wid; r < F32_ROWS; r += 4) {
        const int i = i0 + r;
        const float d2 = d2b[r * SNL_K + (lane & 31)];
        const float s = -d2;
        float m = s;
#pragma unroll
        for (int off = 1; off < 32; off <<= 1)
            m = fmaxf(m, __shfl_xor(m, off, 64));
        const float e = __expf(s - m);
        float ss = e;
#pragma unroll
        for (int off = 1; off < 32; off <<= 1)
            ss += __shfl_xor(ss, off, 64);
        const float logq = (s - m) - __logf(ss);
        const float q = e / ss;
        if (lane < SNL_K) {
            out[1 + (size_t)i * SNL_K + lane] = q;
            const float pv = psim[(size_t)i * SNL_K + lane];
            loss_acc += pv * (__logf(pv + SNL_EPS) - logq);
        }
    }
    __asm__ volatile("" :: "v"(pf));
#pragma unroll
    for (int off = 1; off < 64; off <<= 1)
        loss_acc += __shfl_xor(loss_acc, off, 64);
    if (lane == 0) bred[wid] = loss_acc;
    __syncthreads();
    if (tid == 0) part[b] = bred[0] + bred[1] + bred[2] + bred[3];
}

__global__ __launch_bounds__(256) void snl_loss_reduce(const float* __restrict__ part,
                                                       int npart,
                                                       float* __restrict__ out) {
    double acc = 0.0;
    for (int i = threadIdx.x; i < npart; i += 256) acc += (double)part[i];
#pragma unroll
    for (int off = 1; off < 64; off <<= 1)
        acc += __shfl_xor(acc, off, 64);
    __shared__ double sred[4];
    if ((threadIdx.x & 63) == 0) sred[threadIdx.x >> 6] = acc;
    __syncthreads();
    if (threadIdx.x == 0)
        out[0] = (float)((sred[0] + sred[1] + sred[2] + sred[3]) / (double)SNL_N);
}

extern "C" void kernel_launch(void* const* d_in, const int* in_sizes, int n_in,
                              void* d_out, int out_size, void* d_ws, size_t ws_size,
                              hipStream_t stream) {
    const float* emb  = (const float*)d_in[0];
    const float* psim = (const float*)d_in[1];
    const int*   aidx = (const int*)d_in[2];
    float* out  = (float*)d_out;
    float* part = (float*)d_ws;   // first 8 KB (NBLK floats)

    const size_t need = (size_t)WS_FP16_OFF + (size_t)SNL_N * SNL_D * sizeof(__half);
    if (ws_size >= need) {
        __half* gh = (__half*)((char*)d_ws + WS_FP16_OFF);
        int* ctr = (int*)((char*)d_ws + WS_CTR_OFF);
        snl_quant<<<2048, 256, 0, stream>>>(emb, gh, ctr);
        snl_main_h<<<NBLK, 256, 0, stream>>>(gh, psim, aidx, out, part, ctr);
    } else {
        snl_main_f32<<<F32_NBLK, 256, 0, stream>>>(emb, psim, aidx, out, part);
        snl_loss_reduce<<<1, 256, 0, stream>>>(part, F32_NBLK, out);
    }
}

// Round 4
// 129.264 us; speedup vs baseline: 2.6565x; 1.3120x over previous
//
#include <hip/hip_runtime.h>
#include <hip/hip_fp16.h>
#include <cstddef>
#include <cstdint>

#define SNL_N 50000
#define SNL_K 32
#define SNL_D 128
#define SNL_EPS 1e-12f
#define ROWS_PB 25
#define NBLK 2000          // ~15KB LDS -> 8 blocks/CU (wave-capped) -> all co-resident
#define NPASS 8
#define BUCKET 6250        // fp16 bucket = 1.6 MB << 4 MiB L2/XCD
#define NITEM (ROWS_PB * SNL_K)   // 800 items/block; code fits 10 bits
#define YIPAD 136          // yi LDS row pitch in halves
#define WS_NORM_OFF 8192          // 50000 floats = 200 KB
#define WS_FP16_OFF (8192 + 204800)

// ---------------- fp16 quantization pre-pass (25.6 MB -> 12.8 MB) ----------
// Round-4: also emits norm[i] = sum(h^2) over the QUANTIZED halves (so the
// main kernel's d2 = ni + nj - 2*dot is algebraically identical to
// sum((hi-hj)^2); only fp32 summation-order rounding differs). Rows span 32
// consecutive lanes (idx>>5 = row), so a 5-level shfl tree reduces per-row.
__global__ __launch_bounds__(256) void snl_quant(const float* __restrict__ emb,
                                                 __half* __restrict__ gh,
                                                 float* __restrict__ nrm) {
    const int total = SNL_N * SNL_D / 4;   // float4 items; 32 per row
    for (int idx = blockIdx.x * 256 + threadIdx.x; idx < total; idx += gridDim.x * 256) {
        const float4 v = reinterpret_cast<const float4*>(emb)[idx];
        __half2 h0 = __floats2half2_rn(v.x, v.y);
        __half2 h1 = __floats2half2_rn(v.z, v.w);
        uint2 pk;
        pk.x = *reinterpret_cast<unsigned int*>(&h0);
        pk.y = *reinterpret_cast<unsigned int*>(&h1);
        reinterpret_cast<uint2*>(gh)[idx] = pk;
#if __has_builtin(__builtin_amdgcn_fdot2)
        float sq = __builtin_amdgcn_fdot2(h0, h0, 0.0f, false);
        sq = __builtin_amdgcn_fdot2(h1, h1, sq, false);
#else
        float2 f0 = __half22float2(h0), f1 = __half22float2(h1);
        float sq = f0.x * f0.x + f0.y * f0.y + f1.x * f1.x + f1.y * f1.y;
#endif
        sq += __shfl_xor(sq, 1, 64);
        sq += __shfl_xor(sq, 2, 64);
        sq += __shfl_xor(sq, 4, 64);
        sq += __shfl_xor(sq, 8, 64);
        sq += __shfl_xor(sq, 16, 64);
        if ((idx & 31) == 0) nrm[idx >> 5] = sq;
    }
}

__device__ __forceinline__ float dot2acc(__half2 a, __half2 b, float c) {
#if __has_builtin(__builtin_amdgcn_fdot2)
    return __builtin_amdgcn_fdot2(a, b, c, false);
#else
    float2 fa = __half22float2(a), fb = __half22float2(b);
    c = fmaf(fa.x, fb.x, c);
    return fmaf(fa.y, fb.y, c);
#endif
}

// dot(yi, yj) over 32 halves: 8 fdot2 (round-4: hsub2s dropped via norm trick)
__device__ __forceinline__ float snl_dotAB(const float4& yiv0, const float4& yiv1,
                                           const float4& yjv0, const float4& yjv1) {
    float acc = 0.0f;
    const __half2* hi0 = reinterpret_cast<const __half2*>(&yiv0);
    const __half2* hj0 = reinterpret_cast<const __half2*>(&yjv0);
    const __half2* hi1 = reinterpret_cast<const __half2*>(&yiv1);
    const __half2* hj1 = reinterpret_cast<const __half2*>(&yjv1);
#pragma unroll
    for (int u = 0; u < 4; ++u) acc = dot2acc(hi0[u], hj0[u], acc);
#pragma unroll
    for (int u = 0; u < 4; ++u) acc = dot2acc(hi1[u], hj1[u], acc);
    return acc;
}

// ---------------- main bucketed-pass kernel ---------------------------------
// EXACT round-0 skeleton (45.6 us measured): 2000 co-resident blocks, NPASS=8
// self-paced lockstep bucket passes. The pf-accumulating prefetch is the
// PACING mechanism (pass p+1's pf-add can't retire until pass p's prefetch
// lands -> blocks stay ~1 pass apart -> each XCD L2 holds one 1.6MB bucket).
// Round-2 falsified XCD-staggered order + fire-and-forget global_load_lds
// (blocks drift, FETCH 74.5->115MB, 2.6x slower). Round-3 falsified fused
// last-block reduce: 2000 same-line agent ACQ_REL atomics + L2 wb/inv at
// block exit = ~55us serialized tail. Separate 1-block reduce dispatch is
// ~5us -- keep the 3-kernel structure.
// Round-4 change (inner loop only): d2 = ni + nj - 2*dot with precomputed
// norms -> 8 fdot2 instead of 8 hsub2 + 8 fdot2 per lane per item.
__global__ __launch_bounds__(256, 8) void snl_main_h(
    const __half* __restrict__ gh,
    const float* __restrict__ nrm,
    const float* __restrict__ psim,
    const int* __restrict__ aidx,
    float* __restrict__ out,
    float* __restrict__ part)
{
    const int tid = threadIdx.x;
    const int b   = blockIdx.x;
    const int i0  = b * ROWS_PB;

    __shared__ __half         yib[ROWS_PB * YIPAD];  // 6800 B
    __shared__ float          nib[ROWS_PB];          // 100 B: my rows' norms
    __shared__ float          d2b[NITEM];            // 3200 B
    __shared__ unsigned short idb[NITEM];            // 1600 B
    __shared__ unsigned int   lst[NITEM];            // 3200 B: (a<<10)|(r*32+k)
    __shared__ int cnt[NPASS], offs[NPASS + 1], wrk[NPASS];
    __shared__ float bred[4];

    const float4* gh4 = reinterpret_cast<const float4*>(gh);  // 16B = 8 halves

    // ---- stage yi (400 x 16B chunks) + norms (25) + ids (800) ----
    for (int it = 0; it < 2; ++it) {
        const int idx = it * 256 + tid;
        if (idx < ROWS_PB * 16) {
            const int row = idx >> 4, c = idx & 15;
            *reinterpret_cast<float4*>(&yib[row * YIPAD + c * 8]) =
                gh4[(size_t)(i0 + row) * 16 + c];
        }
    }
    if (tid < ROWS_PB) nib[tid] = nrm[i0 + tid];
    for (int it = 0; it < 4; ++it) {
        const int idx = it * 256 + tid;
        if (idx < NITEM)
            idb[idx] = (unsigned short)aidx[(size_t)i0 * SNL_K + idx];
    }
    if (tid < NPASS) cnt[tid] = 0;
    __syncthreads();

    // ---- counting sort of (r,k) by bucket(anchor), anchor fused in entry ----
    for (int it = 0; it < 4; ++it) {
        const int idx = it * 256 + tid;
        if (idx < NITEM) atomicAdd(&cnt[idb[idx] / BUCKET], 1);
    }
    __syncthreads();
    if (tid == 0) {
        int acc = 0;
        for (int p = 0; p < NPASS; ++p) { offs[p] = acc; wrk[p] = acc; acc += cnt[p]; }
        offs[NPASS] = acc;
    }
    __syncthreads();
    for (int it = 0; it < 4; ++it) {
        const int idx = it * 256 + tid;
        if (idx < NITEM) {
            const unsigned a = idb[idx];
            lst[atomicAdd(&wrk[a / BUCKET], 1)] = (a << 10) | (unsigned)idx;
        }
    }
    __syncthreads();

    // ---- self-paced bucket passes ----
    const int oct  = tid >> 3;   // item slot in a 32-item step (0..31)
    const int dc   = tid & 7;    // 16B chunk; 8 lanes = one 256B fp16 row
    const int xsub = b >> 3;     // 0..249: slice within my XCD group (b%8 ~ XCD)
    float pf = 0.0f;

#pragma unroll 1
    for (int p = 0; p < NPASS; ++p) {
        // prefetch my XCD-group's 25-row slice of fp16 bucket p (400 chunks;
        // 250 blocks/XCD-group x 25 rows = 6250 = full bucket). The pf chain
        // doubles as the cross-pass pacing dependency -- do not remove.
        const size_t pbase = ((size_t)p * BUCKET + (size_t)xsub * ROWS_PB) * 16;
        for (int it = 0; it < 2; ++it) {
            const int idx = it * 256 + tid;
            if (idx < ROWS_PB * 16) pf += gh4[pbase + idx].x;
        }

        // dense processing: full 64-item steps (no predication), then tail
        const int s0 = offs[p], s1 = offs[p + 1];
        const int nfull = (s1 - s0) & ~63;
        int base = s0;
#pragma unroll 1
        for (; base < s0 + nfull; base += 64) {
            const unsigned e0 = lst[base + oct];
            const unsigned e1 = lst[base + 32 + oct];
            const int code0 = (int)(e0 & 1023u), r0 = code0 >> 5, a0 = (int)(e0 >> 10);
            const int code1 = (int)(e1 & 1023u), r1 = code1 >> 5, a1 = (int)(e1 >> 10);
            const float nj0 = nrm[a0];          // broadcast within oct group
            const float nj1 = nrm[a1];
            const float4* jr0 = gh4 + (size_t)a0 * 16;
            const float4* jr1 = gh4 + (size_t)a1 * 16;
            const float4 gj00 = jr0[dc], gj01 = jr0[dc + 8];
            const float4 gj10 = jr1[dc], gj11 = jr1[dc + 8];
            const float4 yi00 = *reinterpret_cast<const float4*>(&yib[r0 * YIPAD + dc * 8]);
            const float4 yi01 = *reinterpret_cast<const float4*>(&yib[r0 * YIPAD + (dc + 8) * 8]);
            const float4 yi10 = *reinterpret_cast<const float4*>(&yib[r1 * YIPAD + dc * 8]);
            const float4 yi11 = *reinterpret_cast<const float4*>(&yib[r1 * YIPAD + (dc + 8) * 8]);
            float acc0 = snl_dotAB(yi00, yi01, gj00, gj01);
            float acc1 = snl_dotAB(yi10, yi11, gj10, gj11);
            acc0 += __shfl_xor(acc0, 1, 64);
            acc1 += __shfl_xor(acc1, 1, 64);
            acc0 += __shfl_xor(acc0, 2, 64);
            acc1 += __shfl_xor(acc1, 2, 64);
            acc0 += __shfl_xor(acc0, 4, 64);
            acc1 += __shfl_xor(acc1, 4, 64);
            if (dc == 0) {
                d2b[code0] = nib[r0] + nj0 - 2.0f * acc0;
                d2b[code1] = nib[r1] + nj1 - 2.0f * acc1;
            }
        }
#pragma unroll 1
        for (; base < s1; base += 32) {
            const int item = base + oct;
            if (item < s1) {
                const unsigned e = lst[item];
                const int code = (int)(e & 1023u);
                const int r    = code >> 5;
                const int a    = (int)(e >> 10);
                const float nj = nrm[a];
                const float4* jr = gh4 + (size_t)a * 16;
                const float4 gj0 = jr[dc], gj1 = jr[dc + 8];
                const float4 yi0 = *reinterpret_cast<const float4*>(&yib[r * YIPAD + dc * 8]);
                const float4 yi1 = *reinterpret_cast<const float4*>(&yib[r * YIPAD + (dc + 8) * 8]);
                float acc = snl_dotAB(yi0, yi1, gj0, gj1);
                acc += __shfl_xor(acc, 1, 64);
                acc += __shfl_xor(acc, 2, 64);
                acc += __shfl_xor(acc, 4, 64);
                if (dc == 0) d2b[code] = nib[r] + nj - 2.0f * acc;
            }
        }
    }
    __syncthreads();

    // ---- softmax + outputs (one wave per row, round-robin) ----
    const int wid  = tid >> 6;
    const int lane = tid & 63;
    float loss_acc = 0.0f;
    for (int r = wid; r < ROWS_PB; r += 4) {
        const int i = i0 + r;
        const float d2 = d2b[r * SNL_K + (lane & 31)];
        const float s = -d2;
        float m = s;
#pragma unroll
        for (int off = 1; off < 32; off <<= 1)
            m = fmaxf(m, __shfl_xor(m, off, 64));
        const float e = __expf(s - m);
        float ss = e;
#pragma unroll
        for (int off = 1; off < 32; off <<= 1)
            ss += __shfl_xor(ss, off, 64);
        const float logq = (s - m) - __logf(ss);
        const float q = e / ss;
        if (lane < SNL_K) {
            out[1 + (size_t)i * SNL_K + lane] = q;
            const float pv = psim[(size_t)i * SNL_K + lane];
            loss_acc += pv * (__logf(pv + SNL_EPS) - logq);
        }
    }

    __asm__ volatile("" :: "v"(pf));   // keep prefetch loads alive

#pragma unroll
    for (int off = 1; off < 64; off <<= 1)
        loss_acc += __shfl_xor(loss_acc, off, 64);
    if (lane == 0) bred[wid] = loss_acc;
    __syncthreads();
    if (tid == 0) part[b] = bred[0] + bred[1] + bred[2] + bred[3];
}

// ---------------- fallback: fp32 kernel (if ws too small) -------------------
#define F32_ROWS 50
#define F32_NBLK 1000
#define F32_NPASS 8
#define F32_BUCKET 6250
__global__ __launch_bounds__(256, 4) void snl_main_f32(
    const float* __restrict__ emb,
    const float* __restrict__ psim,
    const int* __restrict__ aidx,
    float* __restrict__ out,
    float* __restrict__ part)
{
    const int tid = threadIdx.x;
    const int b   = blockIdx.x;
    const int i0  = b * F32_ROWS;

    __shared__ float          yib[F32_ROWS * SNL_D];
    __shared__ float          d2b[F32_ROWS * SNL_K];
    __shared__ unsigned short idb[F32_ROWS * SNL_K];
    __shared__ unsigned short lst[F32_ROWS * SNL_K];
    __shared__ int cnt[F32_NPASS], offs[F32_NPASS + 1], wrk[F32_NPASS];
    __shared__ float bred[4];

    const float4* emb4 = reinterpret_cast<const float4*>(emb);

    for (int it = 0; it < 7; ++it) {
        const int idx = it * 256 + tid;
        if (idx < F32_ROWS * SNL_D / 4)
            reinterpret_cast<float4*>(yib)[idx] = emb4[(size_t)i0 * (SNL_D / 4) + idx];
        if (idx < F32_ROWS * SNL_K)
            idb[idx] = (unsigned short)aidx[(size_t)i0 * SNL_K + idx];
    }
    if (tid < F32_NPASS) cnt[tid] = 0;
    __syncthreads();
    for (int it = 0; it < 7; ++it) {
        const int idx = it * 256 + tid;
        if (idx < F32_ROWS * SNL_K) atomicAdd(&cnt[idb[idx] / F32_BUCKET], 1);
    }
    __syncthreads();
    if (tid == 0) {
        int acc = 0;
        for (int p = 0; p < F32_NPASS; ++p) { offs[p] = acc; wrk[p] = acc; acc += cnt[p]; }
        offs[F32_NPASS] = acc;
    }
    __syncthreads();
    for (int it = 0; it < 7; ++it) {
        const int idx = it * 256 + tid;
        if (idx < F32_ROWS * SNL_K) {
            const int p = idb[idx] / F32_BUCKET;
            lst[atomicAdd(&wrk[p], 1)] = (unsigned short)idx;
        }
    }
    __syncthreads();

    const int oct  = tid >> 3;
    const int dc   = tid & 7;
    const int xsub = b >> 3;
    float pf = 0.0f;

#pragma unroll 1
    for (int p = 0; p < F32_NPASS; ++p) {
        const size_t pbase4 = ((size_t)p * F32_BUCKET + (size_t)xsub * 50) * (SNL_D / 4);
        for (int it = 0; it < 7; ++it) {
            const int idx = it * 256 + tid;
            if (idx < 50 * SNL_D / 4) pf += emb4[pbase4 + idx].x;
        }
        const int s0 = offs[p], s1 = offs[p + 1];
        for (int base = s0; base < s1; base += 32) {
            const int item = base + oct;
            if (item < s1) {
                const int code = (int)lst[item];
                const int r = code >> 5;
                const int a = (int)idb[code];
                const float4* jr = emb4 + (size_t)a * (SNL_D / 4);
                float acc = 0.0f;
#pragma unroll
                for (int it = 0; it < 4; ++it) {
                    const float4 yj = jr[dc + it * 8];
                    const float4 yi =
                        reinterpret_cast<const float4*>(yib)[r * (SNL_D / 4) + dc + it * 8];
                    const float dx = yi.x - yj.x;
                    const float dy = yi.y - yj.y;
                    const float dz = yi.z - yj.z;
                    const float dw = yi.w - yj.w;
                    acc = fmaf(dx, dx, acc);
                    acc = fmaf(dy, dy, acc);
                    acc = fmaf(dz, dz, acc);
                    acc = fmaf(dw, dw, acc);
                }
                acc += __shfl_xor(acc, 1, 64);
                acc += __shfl_xor(acc, 2, 64);
                acc += __shfl_xor(acc, 4, 64);
                if (dc == 0) d2b[code] = acc;
            }
        }
    }
    __syncthreads();

    const int wid  = tid >> 6;
    const int lane = tid & 63;
    float loss_acc = 0.0f;
    for (int r = wid; r < F32_ROWS; r += 4) {
        const int i = i0 + r;
        const float d2 = d2b[r * SNL_K + (lane & 31)];
        const float s = -d2;
        float m = s;
#pragma unroll
        for (int off = 1; off < 32; off <<= 1)
            m = fmaxf(m, __shfl_xor(m, off, 64));
        const float e = __expf(s - m);
        float ss = e;
#pragma unroll
        for (int off = 1; off < 32; off <<= 1)
            ss += __shfl_xor(ss, off, 64);
        const float logq = (s - m) - __logf(ss);
        const float q = e / ss;
        if (lane < SNL_K) {
            out[1 + (size_t)i * SNL_K + lane] = q;
            const float pv = psim[(size_t)i * SNL_K + lane];
            loss_acc += pv * (__logf(pv + SNL_EPS) - logq);
        }
    }
    __asm__ volatile("" :: "v"(pf));
#pragma unroll
    for (int off = 1; off < 64; off <<= 1)
        loss_acc += __shfl_xor(loss_acc, off, 64);
    if (lane == 0) bred[wid] = loss_acc;
    __syncthreads();
    if (tid == 0) part[b] = bred[0] + bred[1] + bred[2] + bred[3];
}

__global__ __launch_bounds__(256) void snl_loss_reduce(const float* __restrict__ part,
                                                       int npart,
                                                       float* __restrict__ out) {
    double acc = 0.0;
    for (int i = threadIdx.x; i < npart; i += 256) acc += (double)part[i];
#pragma unroll
    for (int off = 1; off < 64; off <<= 1)
        acc += __shfl_xor(acc, off, 64);
    __shared__ double sred[4];
    if ((threadIdx.x & 63) == 0) sred[threadIdx.x >> 6] = acc;
    __syncthreads();
    if (threadIdx.x == 0)
        out[0] = (float)((sred[0] + sred[1] + sred[2] + sred[3]) / (double)SNL_N);
}

extern "C" void kernel_launch(void* const* d_in, const int* in_sizes, int n_in,
                              void* d_out, int out_size, void* d_ws, size_t ws_size,
                              hipStream_t stream) {
    const float* emb  = (const float*)d_in[0];
    const float* psim = (const float*)d_in[1];
    const int*   aidx = (const int*)d_in[2];
    float* out  = (float*)d_out;
    float* part = (float*)d_ws;   // first 8 KB (NBLK floats)

    const size_t need = (size_t)WS_FP16_OFF + (size_t)SNL_N * SNL_D * sizeof(__half);
    if (ws_size >= need) {
        float*  nrm = (float*)((char*)d_ws + WS_NORM_OFF);
        __half* gh  = (__half*)((char*)d_ws + WS_FP16_OFF);
        snl_quant<<<2048, 256, 0, stream>>>(emb, gh, nrm);
        snl_main_h<<<NBLK, 256, 0, stream>>>(gh, nrm, psim, aidx, out, part);
        snl_loss_reduce<<<1, 256, 0, stream>>>(part, NBLK, out);
    } else {
        snl_main_f32<<<F32_NBLK, 256, 0, stream>>>(emb, psim, aidx, out, part);
        snl_loss_reduce<<<1, 256, 0, stream>>>(part, F32_NBLK, out);
    }
}